// Round 2
// baseline (515.091 us; speedup 1.0000x reference)
//
#include <hip/hip_runtime.h>

#define BATCH 65536

typedef float f32x4 __attribute__((ext_vector_type(4)));
typedef _Float16 f16x8 __attribute__((ext_vector_type(8)));

__device__ __forceinline__ void async_ld16(const void* g, void* l) {
  __builtin_amdgcn_global_load_lds(
      (const __attribute__((address_space(1))) void*)g,
      (__attribute__((address_space(3))) void*)l, 16, 0, 0);
}

// a0*tanh(x)*sin(a1*x+a2) + a3*x + a4, fast HW transcendentals
__device__ __forceinline__ float act_f(float x, float a0, float a1, float a2,
                                       float a3, float a4) {
  float ax = fabsf(x);
  // tanh(|x|) = (1 - e^{-2|x|}) / (1 + e^{-2|x|})
  float e = __builtin_amdgcn_exp2f(ax * -2.8853900817779268f);
  float th = (1.0f - e) * __builtin_amdgcn_rcpf(1.0f + e);
  th = copysignf(th, x);
  // sin via v_sin_f32 (input in revolutions, fract-reduced)
  float arg = fmaf(a1, x, a2);
  float rev = arg * 0.15915494309189535f;
  rev -= floorf(rev);
  float s = __builtin_amdgcn_sinf(rev);
  return fmaf(a3, x, fmaf(a0 * th, s, a4));
}

// split + transpose weights: W[K][N] fp32 -> Wt_hi/lo[N][K] fp16
__global__ __launch_bounds__(256) void splitT_k(const float* __restrict__ W,
                                                _Float16* __restrict__ hi,
                                                _Float16* __restrict__ lo,
                                                int K, int N) {
  const int i = blockIdx.x * 256 + threadIdx.x;
  if (i >= K * N) return;
  const int k = i / N, n = i % N;
  const float w = W[i];
  const _Float16 h = (_Float16)w;
  hi[(size_t)n * K + k] = h;
  lo[(size_t)n * K + k] = (_Float16)(w - (float)h);
}

// C = A @ B. A: either fp32 [M][K] (AF32, split in-register) or fp16 hi/lo
// planes. B: Wt[N][K] fp16 hi/lo planes. 3-product compensation:
// Ahi*Bhi + Ahi*Blo + Alo*Bhi, fp32 MFMA accumulate.
// Epilogue: bias + activation; FINAL writes fp32, else hi/lo fp16 planes.
// Grid: (N/128, M/128) — N-tiles fastest for A-strip L2 locality.
template <bool AF32, bool FINAL>
__global__ __launch_bounds__(256, 2) void gemm_act(
    const float* __restrict__ Af, const _Float16* __restrict__ Ahi,
    const _Float16* __restrict__ Alo, const _Float16* __restrict__ Bhi,
    const _Float16* __restrict__ Blo, const float* __restrict__ bias,
    const float* __restrict__ ap, _Float16* __restrict__ Chi,
    _Float16* __restrict__ Clo, float* __restrict__ Cout, int K, int N) {
  __shared__ __align__(16) _Float16 sA[AF32 ? 2 : 2 * 128 * 32];
  __shared__ __align__(16) _Float16 sB[2 * 128 * 32];

  const int tid = threadIdx.x;
  const int wv = tid >> 6;
  const int lane = tid & 63;
  const int wm = wv >> 1, wn = wv & 1;
  const int m16 = lane & 15, quad = lane >> 4;
  const int col0 = blockIdx.x * 128;
  const int row0 = blockIdx.y * 128;
  const int crow = lane >> 2;  // staging: row within 16-row chunk
  const int cseg = lane & 3;   // staging: 16B segment within 64B row

  f32x4 acc[4][4];
  const f32x4 zero = {0.f, 0.f, 0.f, 0.f};
#pragma unroll
  for (int i = 0; i < 4; ++i)
#pragma unroll
    for (int j = 0; j < 4; ++j) acc[i][j] = zero;

  const int nk = K >> 5;
  for (int kt = 0; kt < nk; ++kt) {
    const int k0 = kt << 5;
    // stage fp16 planes: chunk c = 16 rows x 32 halfs (1024B); HW scatter is
    // wave-uniform base + lane*16 => lane l -> row l/4, 16B seg l%4
    if (!AF32) {
#pragma unroll
      for (int t = 0; t < 2; ++t) {
        const int c = wv * 2 + t;
        const int r = c * 16 + crow;
        const size_t ga = (size_t)(row0 + r) * K + k0 + cseg * 8;
        async_ld16(Ahi + ga, (void*)&sA[c * 512]);
        async_ld16(Alo + ga, (void*)&sA[128 * 32 + c * 512]);
      }
    }
#pragma unroll
    for (int t = 0; t < 2; ++t) {
      const int c = wv * 2 + t;
      const int r = c * 16 + crow;
      const size_t gb = (size_t)(col0 + r) * K + k0 + cseg * 8;
      async_ld16(Bhi + gb, (void*)&sB[c * 512]);
      async_ld16(Blo + gb, (void*)&sB[128 * 32 + c * 512]);
    }

    f16x8 ah[4], al[4], bh[4], bl[4];
    if (AF32) {
      // direct global A-fragment load + in-register hi/lo split (before the
      // barrier: independent of LDS)
#pragma unroll
      for (int tm = 0; tm < 4; ++tm) {
        const float* p =
            Af + (size_t)(row0 + wm * 64 + tm * 16 + m16) * K + k0 + quad * 8;
        const f32x4 x0 = *(const f32x4*)p;
        const f32x4 x1 = *(const f32x4*)(p + 4);
#pragma unroll
        for (int j = 0; j < 4; ++j) {
          const _Float16 h0 = (_Float16)x0[j];
          ah[tm][j] = h0;
          al[tm][j] = (_Float16)(x0[j] - (float)h0);
          const _Float16 h1 = (_Float16)x1[j];
          ah[tm][4 + j] = h1;
          al[tm][4 + j] = (_Float16)(x1[j] - (float)h1);
        }
      }
    }
    __syncthreads();

    if (!AF32) {
#pragma unroll
      for (int tm = 0; tm < 4; ++tm) {
        const int idx = (wm * 64 + tm * 16 + m16) * 32 + quad * 8;
        ah[tm] = *(const f16x8*)&sA[idx];
        al[tm] = *(const f16x8*)&sA[128 * 32 + idx];
      }
    }
#pragma unroll
    for (int tn = 0; tn < 4; ++tn) {
      const int idx = (wn * 64 + tn * 16 + m16) * 32 + quad * 8;
      bh[tn] = *(const f16x8*)&sB[idx];
      bl[tn] = *(const f16x8*)&sB[128 * 32 + idx];
    }
#pragma unroll
    for (int tm = 0; tm < 4; ++tm)
#pragma unroll
      for (int tn = 0; tn < 4; ++tn) {
        acc[tm][tn] = __builtin_amdgcn_mfma_f32_16x16x32_f16(ah[tm], bh[tn],
                                                             acc[tm][tn], 0, 0, 0);
        acc[tm][tn] = __builtin_amdgcn_mfma_f32_16x16x32_f16(ah[tm], bl[tn],
                                                             acc[tm][tn], 0, 0, 0);
        acc[tm][tn] = __builtin_amdgcn_mfma_f32_16x16x32_f16(al[tm], bh[tn],
                                                             acc[tm][tn], 0, 0, 0);
      }
    __syncthreads();
  }

  // epilogue: C/D layout col=lane&15, row=quad*4+reg (16x16 shape, m89)
#pragma unroll
  for (int tn = 0; tn < 4; ++tn) {
    const int col = col0 + wn * 64 + tn * 16 + m16;
    const float bs = bias[col];
    const float p0 = ap[col * 5 + 0];
    const float p1 = ap[col * 5 + 1];
    const float p2 = ap[col * 5 + 2];
    const float p3 = ap[col * 5 + 3];
    const float p4 = ap[col * 5 + 4];
#pragma unroll
    for (int tm = 0; tm < 4; ++tm) {
      const int row = row0 + wm * 64 + tm * 16 + quad * 4;
#pragma unroll
      for (int r = 0; r < 4; ++r) {
        const float y = act_f(acc[tm][tn][r] + bs, p0, p1, p2, p3, p4);
        const size_t o = (size_t)(row + r) * N + col;
        if (FINAL) {
          Cout[o] = y;
        } else {
          const _Float16 h = (_Float16)y;
          Chi[o] = h;
          Clo[o] = (_Float16)(y - (float)h);
        }
      }
    }
  }
}

// in-place softmax over 256 columns; one wave per row, 4 rows/block
__global__ __launch_bounds__(256) void softmax_rows(float* __restrict__ io) {
  const int wv = threadIdx.x >> 6, lane = threadIdx.x & 63;
  const size_t row = (size_t)blockIdx.x * 4 + wv;
  f32x4* p = (f32x4*)(io + row * 256);
  f32x4 v = p[lane];
  float m = fmaxf(fmaxf(v[0], v[1]), fmaxf(v[2], v[3]));
#pragma unroll
  for (int off = 32; off > 0; off >>= 1) m = fmaxf(m, __shfl_xor(m, off));
  f32x4 e;
  float s = 0.f;
#pragma unroll
  for (int j = 0; j < 4; ++j) {
    e[j] = __builtin_amdgcn_exp2f((v[j] - m) * 1.4426950408889634f);
    s += e[j];
  }
#pragma unroll
  for (int off = 32; off > 0; off >>= 1) s += __shfl_xor(s, off);
  const float inv = __builtin_amdgcn_rcpf(s);
#pragma unroll
  for (int j = 0; j < 4; ++j) e[j] *= inv;
  p[lane] = e;
}

extern "C" void kernel_launch(void* const* d_in, const int* in_sizes, int n_in,
                              void* d_out, int out_size, void* d_ws,
                              size_t ws_size, hipStream_t stream) {
  const float* data = (const float*)d_in[0];
  const float* W1 = (const float*)d_in[1];
  const float* b1 = (const float*)d_in[2];
  const float* a1 = (const float*)d_in[3];
  const float* W2 = (const float*)d_in[4];
  const float* b2 = (const float*)d_in[5];
  const float* a2 = (const float*)d_in[6];
  const float* W3 = (const float*)d_in[7];
  const float* b3 = (const float*)d_in[8];
  const float* a3 = (const float*)d_in[9];
  float* out = (float*)d_out;

  char* ws = (char*)d_ws;
  const size_t KB = 1024, MB = 1024 * 1024;
  // weights: 2 MB at the front of ws
  _Float16* w1hi = (_Float16*)(ws + 0 * KB);       // 256x512 -> 256 KB/plane
  _Float16* w1lo = (_Float16*)(ws + 256 * KB);
  _Float16* w2hi = (_Float16*)(ws + 512 * KB);     // 512x512 -> 512 KB/plane
  _Float16* w2lo = (_Float16*)(ws + 1024 * KB);
  _Float16* w3hi = (_Float16*)(ws + 1536 * KB);    // 512x256 -> 256 KB/plane
  _Float16* w3lo = (_Float16*)(ws + 1792 * KB);
  char* hb = ws + 2 * MB;

  // chunk rows R: h1 hi/lo + h2 hi/lo = R*4096 bytes; fit in ws_size - 2MB
  const size_t avail = (ws_size > 2 * MB) ? ws_size - 2 * MB : 0;
  int R = BATCH;
  while ((size_t)R * 4096 > avail && R > 1024) R >>= 1;
  _Float16* h1hi = (_Float16*)(hb);
  _Float16* h1lo = (_Float16*)(hb + (size_t)R * 1024);
  _Float16* h2hi = (_Float16*)(hb + (size_t)R * 2048);
  _Float16* h2lo = (_Float16*)(hb + (size_t)R * 3072);

  splitT_k<<<(256 * 512 + 255) / 256, 256, 0, stream>>>(W1, w1hi, w1lo, 256, 512);
  splitT_k<<<(512 * 512 + 255) / 256, 256, 0, stream>>>(W2, w2hi, w2lo, 512, 512);
  splitT_k<<<(512 * 256 + 255) / 256, 256, 0, stream>>>(W3, w3hi, w3lo, 512, 256);

  for (int c0 = 0; c0 < BATCH; c0 += R) {
    const float* dc = data + (size_t)c0 * 256;
    float* oc = out + (size_t)c0 * 256;
    gemm_act<true, false><<<dim3(512 / 128, R / 128), 256, 0, stream>>>(
        dc, nullptr, nullptr, w1hi, w1lo, b1, a1, h1hi, h1lo, nullptr, 256, 512);
    gemm_act<false, false><<<dim3(512 / 128, R / 128), 256, 0, stream>>>(
        nullptr, h1hi, h1lo, w2hi, w2lo, b2, a2, h2hi, h2lo, nullptr, 512, 512);
    gemm_act<false, true><<<dim3(256 / 128, R / 128), 256, 0, stream>>>(
        nullptr, h2hi, h2lo, w3hi, w3lo, b3, a3, nullptr, nullptr, oc, 512, 256);
  }

  softmax_rows<<<BATCH / 4, 256, 0, stream>>>(out);
}